// Round 5
// baseline (179.384 us; speedup 1.0000x reference)
//
#include <hip/hip_runtime.h>
#include <hip/hip_bf16.h>
#include <stdint.h>

// QuantizedLinear: out[m][n] = (sum_k x[m][k]*W[n][k]) * scale + bias[n]
// M=256, K=4096, N=11008. W int8-valued -> exact in bf16; scale/bias f32 epilogue.
//
// R5: ZERO synchronization. 688 single-wave blocks (64 thr), no LDS, no
// barriers, no inline asm. Each wave owns 128m x 32n x full-K. W is loaded
// straight into MFMA B-fragment registers (2x dwordx4/lane), cvt'd int->bf16
// in-reg. Pipeline by register dataflow only: W ring-4 (use->reload distance
// ~4 chunks ~ 700cy > HBM latency), A ping-pong (distance 2 chunks > L2
// latency). Compiler emits counted vmcnt; younger W loads stay in flight
// through every wait -> HBM stream never stops. W m-reuse (2x) via L2:
// block map groups both m-halves of an n-strip onto the same XCD (b%8).

#define MM 256
#define NN 11008
#define KK 4096
#define NCH (KK / 32)   // 128 k-chunks of 32

typedef __bf16 bf16x8 __attribute__((ext_vector_type(8)));
typedef float  f32x4  __attribute__((ext_vector_type(4)));

// ---- pass 1: x f32 [256][4096] -> bf16 packed in MFMA A-fragment order ----
// xf[(mb*128 + kb)*64 + l] = bf16x8 { x[mb*16 + (l&15)][kb*32 + (l>>4)*8 + j] }
__global__ void cvt_x_kernel(const float* __restrict__ x, bf16x8* __restrict__ xf) {
    int i  = blockIdx.x * 256 + threadIdx.x;   // 0..131071
    int l  = i & 63;
    int kb = (i >> 6) & 127;
    int mb = i >> 13;
    int m  = mb * 16 + (l & 15);
    int k  = kb * 32 + (l >> 4) * 8;
    const float* p = x + (size_t)m * KK + k;
    float4 v0 = *(const float4*)p;
    float4 v1 = *(const float4*)(p + 4);
    union { __bf16 b[8]; bf16x8 v; } t;
    t.b[0] = (__bf16)v0.x; t.b[1] = (__bf16)v0.y;
    t.b[2] = (__bf16)v0.z; t.b[3] = (__bf16)v0.w;
    t.b[4] = (__bf16)v1.x; t.b[5] = (__bf16)v1.y;
    t.b[6] = (__bf16)v1.z; t.b[7] = (__bf16)v1.w;
    xf[i] = t.v;
}

// ---- pass 2: GEMM, 64 threads/block, 688 blocks ----
__global__ __launch_bounds__(64, 1) void qlin_gemm(
    const bf16x8* __restrict__ xf, const int* __restrict__ w,
    const float* __restrict__ scale, const float* __restrict__ bias,
    float* __restrict__ out) {

    const int lane = threadIdx.x;
    const int b    = blockIdx.x;          // 0..687
    // XCD grouping: hw xcd ~ b%8. Per XCD: 86 blocks = 43 n-strips x 2 m-halves.
    const int xcd  = b & 7;
    const int seq  = b >> 3;              // 0..85
    const int sidx = xcd * 43 + (seq >> 1);   // n-strip 0..343
    const int mh   = seq & 1;             // m-half
    const int n0   = sidx * 32;

    // W as direct B-fragment: lane l covers row n0 + fn*16 + (l&15),
    // ints [(l>>4)*8 + h*4, +4). Two int4 per fragment.
    const int* wp = w + (size_t)(n0 + (lane & 15)) * KK + (lane >> 4) * 8;

    // A fragments (packed): frag(fm, c) = xf[((mh*8+fm)*128 + c)*64 + lane]
    const bf16x8* ab = xf + ((size_t)(mh * 8) * 128) * 64 + lane;

    f32x4 acc[8][2] = {};

    int4 W0[4], W1[4], W2[4], W3[4];   // [fn*2 + h]; ring over chunks c%4
    bf16x8 A0[8], A1[8];               // [fm]; ping-pong over chunks c%2

#define LOADW(Wr, c)                                                        \
    {                                                                       \
        const int c_ = (c);                                                 \
        _Pragma("unroll")                                                   \
        for (int fn = 0; fn < 2; ++fn)                                      \
            _Pragma("unroll")                                               \
            for (int h = 0; h < 2; ++h)                                     \
                Wr[fn * 2 + h] = *(const int4*)(wp + (size_t)fn * 16 * KK + \
                                                c_ * 32 + h * 4);           \
    }
#define LOADA(Ar, c)                                                        \
    {                                                                       \
        const int c_ = (c);                                                 \
        _Pragma("unroll")                                                   \
        for (int fm = 0; fm < 8; ++fm)                                      \
            Ar[fm] = ab[(size_t)(fm * 128 + c_) * 64];                      \
    }
#define COMPUTE(Ar, Wr)                                                     \
    {                                                                       \
        bf16x8 bf[2];                                                       \
        _Pragma("unroll")                                                   \
        for (int fn = 0; fn < 2; ++fn) {                                    \
            union { __bf16 e[8]; bf16x8 v; } t;                             \
            _Pragma("unroll")                                               \
            for (int h = 0; h < 2; ++h) {                                   \
                t.e[h * 4 + 0] = (__bf16)(float)Wr[fn * 2 + h].x;           \
                t.e[h * 4 + 1] = (__bf16)(float)Wr[fn * 2 + h].y;           \
                t.e[h * 4 + 2] = (__bf16)(float)Wr[fn * 2 + h].z;           \
                t.e[h * 4 + 3] = (__bf16)(float)Wr[fn * 2 + h].w;           \
            }                                                               \
            bf[fn] = t.v;                                                   \
        }                                                                   \
        _Pragma("unroll")                                                   \
        for (int fm = 0; fm < 8; ++fm) {                                    \
            acc[fm][0] = __builtin_amdgcn_mfma_f32_16x16x32_bf16(           \
                Ar[fm], bf[0], acc[fm][0], 0, 0, 0);                        \
            acc[fm][1] = __builtin_amdgcn_mfma_f32_16x16x32_bf16(           \
                Ar[fm], bf[1], acc[fm][1], 0, 0, 0);                        \
        }                                                                   \
    }

    // prologue: W(0..3), A(0..1) in flight
    LOADW(W0, 0); LOADW(W1, 1); LOADW(W2, 2); LOADW(W3, 3);
    LOADA(A0, 0); LOADA(A1, 1);

    for (int c4 = 0; c4 < NCH; c4 += 4) {
        const int p4 = (c4 + 4 < NCH) ? c4 + 4 : NCH - 1;  // W prefetch chunks
        const int p2 = (c4 + 2 < NCH) ? c4 + 2 : NCH - 1;  // A prefetch chunks
        COMPUTE(A0, W0); LOADW(W0, p4);     LOADA(A0, p2);
        COMPUTE(A1, W1); LOADW(W1, p4 + ((c4 + 5 < NCH) ? 1 : 0));
                         LOADA(A1, p2 + ((c4 + 3 < NCH) ? 1 : 0));
        COMPUTE(A0, W2); LOADW(W2, p4 + ((c4 + 6 < NCH) ? 2 : 0));
                         LOADA(A0, p2 + ((c4 + 4 < NCH) ? 2 : 0));
        COMPUTE(A1, W3); LOADW(W3, p4 + ((c4 + 7 < NCH) ? 3 : 0));
                         LOADA(A1, p2 + ((c4 + 5 < NCH) ? 3 : 0));
    }
#undef LOADW
#undef LOADA
#undef COMPUTE

    // epilogue: D layout col=lane&15, row=(lane>>4)*4+r; y = acc*scale + bias
    const float sc = scale[0];
    const int ecol  = lane & 15;
    const int erow0 = (lane >> 4) * 4;
#pragma unroll
    for (int fn = 0; fn < 2; ++fn) {
        const int n = n0 + fn * 16 + ecol;
        const float bv = bias[n];
#pragma unroll
        for (int fm = 0; fm < 8; ++fm) {
            const int mrow = mh * 128 + fm * 16 + erow0;
#pragma unroll
            for (int r = 0; r < 4; ++r)
                out[(size_t)(mrow + r) * NN + n] = acc[fm][fn][r] * sc + bv;
        }
    }
}

extern "C" void kernel_launch(void* const* d_in, const int* in_sizes, int n_in,
                              void* d_out, int out_size, void* d_ws, size_t ws_size,
                              hipStream_t stream) {
    const float* x     = (const float*)d_in[0];
    const int*   wq    = (const int*)d_in[1];
    const float* scale = (const float*)d_in[2];
    const float* bias  = (const float*)d_in[3];
    float* out = (float*)d_out;
    bf16x8* xf = (bf16x8*)d_ws;   // 2 MB packed-A scratch

    cvt_x_kernel<<<dim3(MM * KK / (256 * 8)), dim3(256), 0, stream>>>(x, xf);
    qlin_gemm<<<dim3((NN / 32) * 2), dim3(64), 0, stream>>>(xf, wq, scale, bias, out);
}

// Round 6
// 66.663 us; speedup vs baseline: 2.6909x; 2.6909x over previous
//
#include <hip/hip_runtime.h>
#include <hip/hip_bf16.h>
#include <stdint.h>

// QuantizedLinear: out[m][n] = (sum_k x[m][k]*W[n][k]) * scale + bias[n]
// M=256, K=4096, N=11008. W int8-valued -> exact in bf16; scale/bias f32 epilogue.
//
// R6: m201-style pipeline. W staged via global_load_lds (int32) into a 5-slot
// LDS ring, 4 iters ahead; consumed after counted s_waitcnt vmcnt(16) + raw
// s_barrier (vmcnt NEVER drained). A = packed bf16 frags, global->reg, 2-iter
// lookahead issued at TOP of iter (in-order vmcnt: A(t)-wait then only forces
// a 3-iter-old W glds, ~1200cy > HBM latency). LDS W rows XOR-swizzled via
// pre-swizzled per-lane GLOBAL source (slot s of row r lives at s^(r&15)):
// B-frag reads spread over 16 slots -> 2-way banks = free.

#define MM 256
#define NN 11008
#define KK 4096
#define NT 64            // K-tiles of 64 ints
#define WSLOT 8192       // 32 rows x 256B per W LDS slot
#define NSLOT 5

typedef __bf16 bf16x8 __attribute__((ext_vector_type(8)));
typedef float  f32x4  __attribute__((ext_vector_type(4)));

// ---- pass 1: x f32 [256][4096] -> bf16 packed in MFMA A-fragment order ----
// xf[(mb*128 + kb)*64 + l] = bf16x8 { x[mb*16 + (l&15)][kb*32 + (l>>4)*8 + j] }
__global__ void cvt_x_kernel(const float* __restrict__ x, bf16x8* __restrict__ xf) {
    int i  = blockIdx.x * 256 + threadIdx.x;   // 0..131071
    int l  = i & 63;
    int kb = (i >> 6) & 127;
    int mb = i >> 13;
    int m  = mb * 16 + (l & 15);
    int k  = kb * 32 + (l >> 4) * 8;
    const float* p = x + (size_t)m * KK + k;
    float4 v0 = *(const float4*)p;
    float4 v1 = *(const float4*)(p + 4);
    union { __bf16 b[8]; bf16x8 v; } t;
    t.b[0] = (__bf16)v0.x; t.b[1] = (__bf16)v0.y;
    t.b[2] = (__bf16)v0.z; t.b[3] = (__bf16)v0.w;
    t.b[4] = (__bf16)v1.x; t.b[5] = (__bf16)v1.y;
    t.b[6] = (__bf16)v1.z; t.b[7] = (__bf16)v1.w;
    xf[i] = t.v;
}

// ---- pass 2: GEMM. 256 thr (4 waves); wave w: m-rows [mh*128+w*32,+32) x 32 n ----
__global__ __launch_bounds__(256, 4) void qlin_gemm(
    const bf16x8* __restrict__ xf, const int* __restrict__ wq,
    const float* __restrict__ scale, const float* __restrict__ bias,
    float* __restrict__ out) {

    __shared__ __align__(16) char wsm[NSLOT * WSLOT];   // 40 KB

    const int tid  = threadIdx.x;
    const int lane = tid & 63;
    const int wid  = tid >> 6;          // 0..3
    const int nl   = lane & 15;
    const int qh   = lane >> 4;

    // XCD-paired block map (R5; FETCH evidence says it helps L2/L3 W reuse):
    // per XCD: 43 n-strips x 2 m-halves, mh fastest.
    const int bid   = blockIdx.x;       // 0..687
    const int xcd   = bid & 7;
    const int seq   = bid >> 3;         // 0..85
    const int strip = xcd * 43 + (seq >> 1);
    const int mh    = seq & 1;
    const int n0    = strip * 32;

    // --- W glds: wave stages chunks c0=wid*2, c0+1 (4 rows each) ---
    // chunk c, lane: tile-row r = 4c+qh, lands at LDS slot-in-row nl;
    // fetch data-slot sg = nl ^ (r&15)  => global int off (k-tile t):
    //   (n0+r)*KK + t*64 + sg*4
    const int c0 = wid * 2;
    const int r0 = 4 * c0 + qh, r1 = r0 + 4;
    const int* wsrc0 = wq + (size_t)(n0 + r0) * KK + ((nl ^ (r0 & 15)) * 4);
    const int* wsrc1 = wq + (size_t)(n0 + r1) * KK + ((nl ^ (r1 & 15)) * 4);

    // --- A fragments (packed, per-wave-private) ---
    const bf16x8* abase = xf + ((size_t)(mh * 8 + wid * 2) * 128) * 64 + lane;

    f32x4 acc[2][2] = {};
    bf16x8 A0[4], A1[4], A2[4], A3[4];   // [fmr*2+kb]; static ring of 4

    auto stageW = [&](int t, int slot) {
        char* d = wsm + slot * WSLOT + c0 * 1024;    // wave-uniform dest
        __builtin_amdgcn_global_load_lds(
            (const __attribute__((address_space(1))) void*)(wsrc0 + t * 64),
            (__attribute__((address_space(3))) void*)d, 16, 0, 0);
        __builtin_amdgcn_global_load_lds(
            (const __attribute__((address_space(1))) void*)(wsrc1 + t * 64),
            (__attribute__((address_space(3))) void*)(d + 1024), 16, 0, 0);
    };
    auto loadA = [&](bf16x8 (&A)[4], int t) {
#pragma unroll
        for (int fmr = 0; fmr < 2; ++fmr)
#pragma unroll
            for (int kb = 0; kb < 2; ++kb)
                A[fmr * 2 + kb] = abase[((size_t)fmr * 128 + t * 2 + kb) * 64];
    };
    auto compute = [&](const bf16x8 (&A)[4], int slot) {
        const char* B = wsm + slot * WSLOT;
#pragma unroll
        for (int kb = 0; kb < 2; ++kb) {
            bf16x8 bfrag[2];
#pragma unroll
            for (int fn = 0; fn < 2; ++fn) {
                const int n  = fn * 16 + nl;             // n&15 == nl
                const int s0 = kb * 8 + qh * 2;
                const char* row = B + n * 256;
                int4 w0 = *(const int4*)(row + ((s0 ^ nl) * 16));
                int4 w1 = *(const int4*)(row + (((s0 + 1) ^ nl) * 16));
                union { __bf16 e[8]; bf16x8 v; } t_;
                t_.e[0] = (__bf16)(float)w0.x; t_.e[1] = (__bf16)(float)w0.y;
                t_.e[2] = (__bf16)(float)w0.z; t_.e[3] = (__bf16)(float)w0.w;
                t_.e[4] = (__bf16)(float)w1.x; t_.e[5] = (__bf16)(float)w1.y;
                t_.e[6] = (__bf16)(float)w1.z; t_.e[7] = (__bf16)(float)w1.w;
                bfrag[fn] = t_.v;
            }
#pragma unroll
            for (int fmr = 0; fmr < 2; ++fmr) {
                acc[fmr][0] = __builtin_amdgcn_mfma_f32_16x16x32_bf16(
                    A[fmr * 2 + kb], bfrag[0], acc[fmr][0], 0, 0, 0);
                acc[fmr][1] = __builtin_amdgcn_mfma_f32_16x16x32_bf16(
                    A[fmr * 2 + kb], bfrag[1], acc[fmr][1], 0, 0, 0);
            }
        }
    };

    // ---- prologue: W tiles 0..3 staged (OLDEST in vmcnt FIFO), then A(0),A(1) ----
    stageW(0, 0); stageW(1, 1); stageW(2, 2); stageW(3, 3);
    loadA(A0, 0); loadA(A1, 1);

    // ---- iter t: loadA(t+2); stageW(t+4); vmcnt(16); barrier; compute(t); barrier ----
    // steady outstanding at wait: W(t..t+4)=10 + A(t),A(t+1),A(t+2)=12 -> 22;
    // vmcnt(16) retires the 6 oldest (W(t), W(t+1), half of A(t)).
#define ITER(T, AU, AL)                                              \
    {                                                                \
        const int t_ = (T);                                          \
        loadA(AL, (t_ + 2 < NT) ? t_ + 2 : NT - 1);                  \
        stageW((t_ + 4 < NT) ? t_ + 4 : NT - 1, (t_ + 4) % NSLOT);   \
        __builtin_amdgcn_sched_barrier(0);                           \
        asm volatile("s_waitcnt vmcnt(16)" ::: "memory");            \
        __builtin_amdgcn_s_barrier();                                \
        compute(AU, t_ % NSLOT);                                     \
        __builtin_amdgcn_s_barrier();                                \
    }

#pragma unroll 1
    for (int tq = 0; tq < NT / 4; ++tq) {
        const int t0 = tq * 4;
        ITER(t0 + 0, A0, A2)
        ITER(t0 + 1, A1, A3)
        ITER(t0 + 2, A2, A0)
        ITER(t0 + 3, A3, A1)
    }
#undef ITER

    // ---- epilogue: D layout col=lane&15, row=qh*4+r; y = acc*scale + bias ----
    const float sc = scale[0];
    const int erow0 = qh * 4;
#pragma unroll
    for (int fn = 0; fn < 2; ++fn) {
        const int n = n0 + fn * 16 + nl;
        const float bv = bias[n];
#pragma unroll
        for (int fmr = 0; fmr < 2; ++fmr) {
            const int m = mh * 128 + wid * 32 + fmr * 16 + erow0;
#pragma unroll
            for (int r = 0; r < 4; ++r)
                out[(size_t)(m + r) * NN + n] = acc[fmr][fn][r] * sc + bv;
        }
    }
}

extern "C" void kernel_launch(void* const* d_in, const int* in_sizes, int n_in,
                              void* d_out, int out_size, void* d_ws, size_t ws_size,
                              hipStream_t stream) {
    const float* x     = (const float*)d_in[0];
    const int*   wq    = (const int*)d_in[1];
    const float* scale = (const float*)d_in[2];
    const float* bias  = (const float*)d_in[3];
    float* out = (float*)d_out;
    bf16x8* xf = (bf16x8*)d_ws;   // 2 MB packed-A scratch

    cvt_x_kernel<<<dim3(MM * KK / (256 * 8)), dim3(256), 0, stream>>>(x, xf);
    qlin_gemm<<<dim3(688), dim3(256), 0, stream>>>(xf, wq, scale, bias, out);
}

// Round 7
// 60.326 us; speedup vs baseline: 2.9736x; 1.1050x over previous
//
#include <hip/hip_runtime.h>
#include <hip/hip_bf16.h>
#include <stdint.h>

// QuantizedLinear: out[m][n] = (sum_k x[m][k]*W[n][k]) * scale + bias[n]
// M=256, K=4096, N=11008. W int8-valued -> exact in bf16; scale/bias f32 epilogue.
//
// R7 (from R6 post-mortem: throughput-bound on LDS reads + read-side cvt VALU):
//  - W cvt moved to WRITE side: global->reg (int4 x2/thread, 4-iter lookahead,
//    4-slot named reg ring) -> cvt (12 VALU/thread) -> ONE ds_write_b128/wave
//    into an 8-slot bf16 LDS ring (rows padded to 144B: reads are 2-way bank
//    aliasing = free, no XOR needed). LDS reads halve (bf16), cvt drops 4x.
//  - 8-slot ring => WAR distance 8 iters => ONE s_barrier + lgkmcnt(0)/iter.
//  - All VMEM deps are register deps -> compiler emits exact counted vmcnt;
//    loadA(t+2) issued BEFORE loadW(t+4) so A-waits never force young W loads.
//  - A: packed bf16 frags (cvt_x pass), global->reg from L2, 4 static bufs.

#define MM 256
#define NN 11008
#define KK 4096
#define NT 64            // K-tiles of 64 ints
#define ROWB 144         // bf16 row pitch (128B data + 16B pad)
#define SLOTB (32 * ROWB)  // 4608 B per LDS slot
#define NSLOT 8

typedef __bf16 bf16x8 __attribute__((ext_vector_type(8)));
typedef float  f32x4  __attribute__((ext_vector_type(4)));

// ---- pass 1: x f32 [256][4096] -> bf16 packed in MFMA A-fragment order ----
// xf[(mb*128 + kb)*64 + l] = bf16x8 { x[mb*16 + (l&15)][kb*32 + (l>>4)*8 + j] }
__global__ void cvt_x_kernel(const float* __restrict__ x, bf16x8* __restrict__ xf) {
    int i  = blockIdx.x * 256 + threadIdx.x;   // 0..131071
    int l  = i & 63;
    int kb = (i >> 6) & 127;
    int mb = i >> 13;
    int m  = mb * 16 + (l & 15);
    int k  = kb * 32 + (l >> 4) * 8;
    const float* p = x + (size_t)m * KK + k;
    float4 v0 = *(const float4*)p;
    float4 v1 = *(const float4*)(p + 4);
    union { __bf16 b[8]; bf16x8 v; } t;
    t.b[0] = (__bf16)v0.x; t.b[1] = (__bf16)v0.y;
    t.b[2] = (__bf16)v0.z; t.b[3] = (__bf16)v0.w;
    t.b[4] = (__bf16)v1.x; t.b[5] = (__bf16)v1.y;
    t.b[6] = (__bf16)v1.z; t.b[7] = (__bf16)v1.w;
    xf[i] = t.v;
}

// ---- pass 2: GEMM. 256 thr (4 waves); wave w: m-rows [mh*128+w*32,+32) x 32 n ----
__global__ __launch_bounds__(256, 3) void qlin_gemm(
    const bf16x8* __restrict__ xf, const int* __restrict__ wq,
    const float* __restrict__ scale, const float* __restrict__ bias,
    float* __restrict__ out) {

    __shared__ __align__(16) char wsm[NSLOT * SLOTB];   // 36 KB

    const int tid  = threadIdx.x;
    const int lane = tid & 63;
    const int wid  = tid >> 6;          // 0..3
    const int nl   = lane & 15;
    const int qh   = lane >> 4;

    // XCD-paired block map: per XCD 43 n-strips x 2 m-halves, mh fastest.
    const int bid   = blockIdx.x;       // 0..687
    const int xcd   = bid & 7;
    const int seq   = bid >> 3;         // 0..85
    const int strip = xcd * 43 + (seq >> 1);
    const int mh    = seq & 1;
    const int n0    = strip * 32;

    // --- W staging: thread t -> tile-row r = t>>3, k-slot s = t&7 (8 ints) ---
    const int wr = tid >> 3;
    const int ws = tid & 7;
    const int* wsrc = wq + (size_t)(n0 + wr) * KK + ws * 8;
    const int wdst  = wr * ROWB + ws * 16;

    // --- B fragment read offsets: row = fn*16+nl, byte = row*144 + kb*64 + qh*16 ---
    const int brd0 = nl * ROWB + qh * 16;           // fn=0 base (+ kb*64)
    const int brd1 = (16 + nl) * ROWB + qh * 16;    // fn=1 base

    // --- A fragments (packed, per-wave-private) ---
    const bf16x8* abase = xf + ((size_t)(mh * 8 + wid * 2) * 128) * 64 + lane;

    f32x4 acc[2][2] = {};
    int4   R0[2], R1[2], R2[2], R3[2];      // W reg ring, tile u in slot u&3
    bf16x8 A0[4], A1[4], A2[4], A3[4];      // A bufs, tile u in buf u&3

    auto loadW = [&](int4 (&r)[2], int t) {
        const int* p = wsrc + t * 64;
        r[0] = *(const int4*)p;
        r[1] = *(const int4*)(p + 4);
    };
    auto loadA = [&](bf16x8 (&A)[4], int t) {
#pragma unroll
        for (int fmr = 0; fmr < 2; ++fmr)
#pragma unroll
            for (int kb = 0; kb < 2; ++kb)
                A[fmr * 2 + kb] = abase[((size_t)fmr * 128 + t * 2 + kb) * 64];
    };
    auto writeW = [&](const int4 (&r)[2], int slot) {
        union { __bf16 e[8]; bf16x8 v; } c;
        c.e[0] = (__bf16)(float)r[0].x; c.e[1] = (__bf16)(float)r[0].y;
        c.e[2] = (__bf16)(float)r[0].z; c.e[3] = (__bf16)(float)r[0].w;
        c.e[4] = (__bf16)(float)r[1].x; c.e[5] = (__bf16)(float)r[1].y;
        c.e[6] = (__bf16)(float)r[1].z; c.e[7] = (__bf16)(float)r[1].w;
        *(bf16x8*)(wsm + slot * SLOTB + wdst) = c.v;
    };
    auto compute = [&](const bf16x8 (&A)[4], int slot) {
        const char* B = wsm + slot * SLOTB;
#pragma unroll
        for (int kb = 0; kb < 2; ++kb) {
            bf16x8 b0 = *(const bf16x8*)(B + brd0 + kb * 64);
            bf16x8 b1 = *(const bf16x8*)(B + brd1 + kb * 64);
#pragma unroll
            for (int fmr = 0; fmr < 2; ++fmr) {
                acc[fmr][0] = __builtin_amdgcn_mfma_f32_16x16x32_bf16(
                    A[fmr * 2 + kb], b0, acc[fmr][0], 0, 0, 0);
                acc[fmr][1] = __builtin_amdgcn_mfma_f32_16x16x32_bf16(
                    A[fmr * 2 + kb], b1, acc[fmr][1], 0, 0, 0);
            }
        }
    };

    // ---- prologue: W(0..3) -> reg ring; A(0),A(1); tiles 0,1 -> LDS slots 0,1 ----
    loadW(R0, 0); loadW(R1, 1); loadW(R2, 2); loadW(R3, 3);
    loadA(A0, 0); loadA(A1, 1);
    writeW(R0, 0);
    writeW(R1, 1);
    asm volatile("s_waitcnt lgkmcnt(0)" ::: "memory");
    __builtin_amdgcn_s_barrier();

    // ---- iter t: loadA(t+2); loadW(t+4); writeW(tile t+2 -> slot (t+2)&7);
    //              compute(t, slot t&7); lgkm(0); barrier ----
#define STEP(T, AL, WL, WS, AC)                                      \
    {                                                                \
        const int t_ = (T);                                          \
        loadA(AL, (t_ + 2 < NT) ? t_ + 2 : NT - 1);                  \
        loadW(WL, (t_ + 4 < NT) ? t_ + 4 : NT - 1);                  \
        writeW(WS, (t_ + 2) & 7);                                    \
        compute(AC, t_ & 7);                                         \
        asm volatile("s_waitcnt lgkmcnt(0)" ::: "memory");           \
        __builtin_amdgcn_s_barrier();                                \
    }

#pragma unroll 1
    for (int tq = 0; tq < NT / 4; ++tq) {
        const int t0 = tq * 4;
        STEP(t0 + 0, A2, R0, R2, A0)   // load A(t+2)->buf2, W(t+4)->reg0; write tile t+2 (reg2)
        STEP(t0 + 1, A3, R1, R3, A1)
        STEP(t0 + 2, A0, R2, R0, A2)
        STEP(t0 + 3, A1, R3, R1, A3)
    }
#undef STEP

    // ---- epilogue: D layout col=lane&15, row=qh*4+r; y = acc*scale + bias ----
    const float sc = scale[0];
    const int erow0 = qh * 4;
#pragma unroll
    for (int fn = 0; fn < 2; ++fn) {
        const int n = n0 + fn * 16 + nl;
        const float bv = bias[n];
#pragma unroll
        for (int fmr = 0; fmr < 2; ++fmr) {
            const int m = mh * 128 + wid * 32 + fmr * 16 + erow0;
#pragma unroll
            for (int r = 0; r < 4; ++r)
                out[(size_t)(m + r) * NN + n] = acc[fmr][fn][r] * sc + bv;
        }
    }
}

extern "C" void kernel_launch(void* const* d_in, const int* in_sizes, int n_in,
                              void* d_out, int out_size, void* d_ws, size_t ws_size,
                              hipStream_t stream) {
    const float* x     = (const float*)d_in[0];
    const int*   wq    = (const int*)d_in[1];
    const float* scale = (const float*)d_in[2];
    const float* bias  = (const float*)d_in[3];
    float* out = (float*)d_out;
    bf16x8* xf = (bf16x8*)d_ws;   // 2 MB packed-A scratch

    cvt_x_kernel<<<dim3(MM * KK / (256 * 8)), dim3(256), 0, stream>>>(x, xf);
    qlin_gemm<<<dim3(688), dim3(256), 0, stream>>>(xf, wq, scale, bias, out);
}